// Round 8
// baseline (259.277 us; speedup 1.0000x reference)
//
#include <hip/hip_runtime.h>

#define IW 512
#define IH 512
#define NPIX (IW * IH)
#define BIGPID 0x7FFFFFFF
#define INFBITS 0x7F800000u

__global__ void init_bufs(unsigned* __restrict__ zb, int* __restrict__ pb) {
    int i = blockIdx.x * blockDim.x + threadIdx.x;
    if (i < NPIX) { zb[i] = INFBITS; pb[i] = BIGPID; }
}

// f32 mirror of the XLA-on-gfx950 compiled reference graph:
//  - divisions lowered as a * v_rcp_f32(b)  (XLA fast-div; NOT correctly
//    rounded — this is the hypothesized 1-ulp px/py perturbation site)
//  - r2 contracted as fma(dx,dx, dy*dy)     (LLVM greedy contraction)
//  - all other ops singly-rounded (contract(off)); matmul terms exact.
__device__ __forceinline__ bool project_voxel(
        const float* __restrict__ vox, const float* __restrict__ m1,
        const float* __restrict__ m2, int n,
        float& px, float& py, float& vz) {
#pragma clang fp contract(off)
    float x  = vox[n * 6 + 0];
    float y  = vox[n * 6 + 1];
    float z0 = vox[n * 6 + 2];

    // view_h = [x,y,z,1] @ world2view (left-fold)
    float vh0 = ((x * m1[0]  + y * m1[4])  + z0 * m1[8])  + m1[12];
    float vh1 = ((x * m1[1]  + y * m1[5])  + z0 * m1[9])  + m1[13];
    float vh2 = ((x * m1[2]  + y * m1[6])  + z0 * m1[10]) + m1[14];
    float vh3 = ((x * m1[3]  + y * m1[7])  + z0 * m1[11]) + m1[15];

    float wv  = (fabsf(vh3) > 1e-8f) ? vh3 : 1.0f;
    float rwv = __builtin_amdgcn_rcpf(wv);     // fast reciprocal
    float vx  = vh0 * rwv;
    float vy  = vh1 * rwv;
    vz        = vh2 * rwv;

    // clip = [vx,vy,vz,1] @ proj (cols 0,1,3)
    float cl0 = ((vx * m2[0] + vy * m2[4]) + vz * m2[8])  + m2[12];
    float cl1 = ((vx * m2[1] + vy * m2[5]) + vz * m2[9])  + m2[13];
    float cl3 = ((vx * m2[3] + vy * m2[7]) + vz * m2[11]) + m2[15];

    if (!(fabsf(cl3) > 1e-8f)) return false;  // valid: |w| > 1e-8 (rejects NaN)
    if (!(vz > 1e-6f)) return false;          // valid: z > 1e-6  (rejects NaN)

    float rw   = __builtin_amdgcn_rcpf(cl3);  // fast reciprocal (THE site)
    float ndcx = cl0 * rw;
    float ndcy = cl1 * rw;
    px = ((ndcx + 1.0f) * 0.5f) * (float)IW;
    py = ((ndcy + 1.0f) * 0.5f) * (float)IH;
    return true;
}

// PASS 1: zb[pix] = min z-bits (uint order == float order for z > 0).
// PASS 2: pb[pix] = min pid among splats whose z equals the buffer min.
template <int PASS>
__global__ __launch_bounds__(256) void splat(
        const float* __restrict__ vox, const float* __restrict__ m1,
        const float* __restrict__ m2, unsigned* __restrict__ zb,
        int* __restrict__ pb, int N) {
#pragma clang fp contract(off)
    int n = blockIdx.x * blockDim.x + threadIdx.x;
    if (n >= N) return;

    float px, py, vz;
    if (!project_voxel(vox, m1, m2, n, px, py, vz)) return;

    float fx = floorf(px);
    float fy = floorf(py);
    // whole 3x3 footprint off-screen (also rejects huge/inf/NaN px,py)
    if (!(fx >= -1.0f && fx <= (float)IW && fy >= -1.0f && fy <= (float)IH))
        return;

    for (int oy = -1; oy <= 1; ++oy) {
        for (int ox = -1; ox <= 1; ++ox) {
            float ixf = fx + (float)ox;   // exact (small ints)
            float iyf = fy + (float)oy;
            if (!(ixf >= 0.0f && ixf < (float)IW &&
                  iyf >= 0.0f && iyf < (float)IH)) continue;
            float dx = (ixf + 0.5f) - px;   // (ix+0.5) exact, one rounding
            float dy = (iyf + 0.5f) - py;
            float r2 = fmaf(dx, dx, dy * dy);   // LLVM-contracted form
            if (!(r2 <= 1.0f)) continue;
            int pix = (int)iyf * IW + (int)ixf;
            if (PASS == 1) {
                atomicMin(&zb[pix], __float_as_uint(vz));
            } else {
                if (vz == __uint_as_float(zb[pix])) {
                    int pid = n * 9 + (oy + 1) * 3 + (ox + 1);
                    atomicMin(&pb[pix], pid);
                }
            }
        }
    }
}

__global__ void resolve(const int* __restrict__ pb,
                        const float* __restrict__ vox,
                        float* __restrict__ out) {
    int p = blockIdx.x * blockDim.x + threadIdx.x;
    if (p >= NPIX) return;
    int pid = pb[p];
    float r = 0.0f, g = 0.0f, b = 0.0f;
    if (pid != BIGPID) {
        int n = pid / 9;
        r = vox[n * 6 + 3];
        g = vox[n * 6 + 4];
        b = vox[n * 6 + 5];
    }
    out[p * 3 + 0] = r;
    out[p * 3 + 1] = g;
    out[p * 3 + 2] = b;
}

extern "C" void kernel_launch(void* const* d_in, const int* in_sizes, int n_in,
                              void* d_out, int out_size, void* d_ws, size_t ws_size,
                              hipStream_t stream) {
    const float* vox = (const float*)d_in[0];
    const float* m1  = (const float*)d_in[1];
    const float* m2  = (const float*)d_in[2];
    float* out = (float*)d_out;
    int N = in_sizes[0] / 6;

    unsigned* zb = (unsigned*)d_ws;
    int*      pb = (int*)((char*)d_ws + (size_t)NPIX * sizeof(unsigned));

    init_bufs<<<(NPIX + 255) / 256, 256, 0, stream>>>(zb, pb);
    int blocks = (N + 255) / 256;
    splat<1><<<blocks, 256, 0, stream>>>(vox, m1, m2, zb, pb, N);
    splat<2><<<blocks, 256, 0, stream>>>(vox, m1, m2, zb, pb, N);
    resolve<<<(NPIX + 255) / 256, 256, 0, stream>>>(pb, vox, out);
}

// Round 9
// 164.122 us; speedup vs baseline: 1.5798x; 1.5798x over previous
//
#include <hip/hip_runtime.h>

#define IW 512
#define IH 512
#define NPIX (IW * IH)
#define EMPTY_KEY 0xFFFFFFFFFFFFFFFFull

__global__ void init_bufs(unsigned long long* __restrict__ kb) {
    int i = blockIdx.x * blockDim.x + threadIdx.x;
    if (i < NPIX) kb[i] = EMPTY_KEY;
}

// f32 mirror of the XLA-on-gfx950 compiled reference graph (FROZEN — this
// exact recipe passed with absmax 0.0 in round 8):
//  - divisions lowered as a * v_rcp_f32(b)
//  - r2 contracted as fma(dx,dx, dy*dy)
//  - all other ops singly-rounded (contract(off)); matmul terms exact.
__device__ __forceinline__ bool project_voxel(
        const float* __restrict__ vox, const float* __restrict__ m1,
        const float* __restrict__ m2, int n,
        float& px, float& py, float& vz) {
#pragma clang fp contract(off)
    float x  = vox[n * 6 + 0];
    float y  = vox[n * 6 + 1];
    float z0 = vox[n * 6 + 2];

    float vh0 = ((x * m1[0]  + y * m1[4])  + z0 * m1[8])  + m1[12];
    float vh1 = ((x * m1[1]  + y * m1[5])  + z0 * m1[9])  + m1[13];
    float vh2 = ((x * m1[2]  + y * m1[6])  + z0 * m1[10]) + m1[14];
    float vh3 = ((x * m1[3]  + y * m1[7])  + z0 * m1[11]) + m1[15];

    float wv  = (fabsf(vh3) > 1e-8f) ? vh3 : 1.0f;
    float rwv = __builtin_amdgcn_rcpf(wv);
    float vx  = vh0 * rwv;
    float vy  = vh1 * rwv;
    vz        = vh2 * rwv;

    float cl0 = ((vx * m2[0] + vy * m2[4]) + vz * m2[8])  + m2[12];
    float cl1 = ((vx * m2[1] + vy * m2[5]) + vz * m2[9])  + m2[13];
    float cl3 = ((vx * m2[3] + vy * m2[7]) + vz * m2[11]) + m2[15];

    if (!(fabsf(cl3) > 1e-8f)) return false;  // valid: |w| > 1e-8 (rejects NaN)
    if (!(vz > 1e-6f)) return false;          // valid: z > 1e-6  (rejects NaN)

    float rw   = __builtin_amdgcn_rcpf(cl3);
    float ndcx = cl0 * rw;
    float ndcy = cl1 * rw;
    px = ((ndcx + 1.0f) * 0.5f) * (float)IW;
    py = ((ndcy + 1.0f) * 0.5f) * (float)IH;
    return true;
}

// Single-pass splat: lexicographic min over packed (zbits<<32 | pid).
// For z > 0, u64 bit order == (z, pid) lex order == reference's
// min-z-then-min-pid (pid = n*9 + k < 2^25 fits low word).
// Read-before-atomic: key values at a pixel decrease monotonically, so a
// stale read is >= the true current value; we skip only when the observed
// key is already smaller than ours, which is then guaranteed still true.
__global__ __launch_bounds__(256) void splat(
        const float* __restrict__ vox, const float* __restrict__ m1,
        const float* __restrict__ m2, unsigned long long* __restrict__ kb,
        int N) {
#pragma clang fp contract(off)
    int n = blockIdx.x * blockDim.x + threadIdx.x;
    if (n >= N) return;

    float px, py, vz;
    if (!project_voxel(vox, m1, m2, n, px, py, vz)) return;

    float fx = floorf(px);
    float fy = floorf(py);
    if (!(fx >= -1.0f && fx <= (float)IW && fy >= -1.0f && fy <= (float)IH))
        return;

    unsigned long long zhi = ((unsigned long long)__float_as_uint(vz)) << 32;
    unsigned basepid = (unsigned)n * 9u;

    for (int oy = -1; oy <= 1; ++oy) {
        for (int ox = -1; ox <= 1; ++ox) {
            float ixf = fx + (float)ox;
            float iyf = fy + (float)oy;
            if (!(ixf >= 0.0f && ixf < (float)IW &&
                  iyf >= 0.0f && iyf < (float)IH)) continue;
            float dx = (ixf + 0.5f) - px;
            float dy = (iyf + 0.5f) - py;
            float r2 = fmaf(dx, dx, dy * dy);   // frozen contraction form
            if (!(r2 <= 1.0f)) continue;
            int pix = (int)iyf * IW + (int)ixf;
            unsigned pid = basepid + (unsigned)((oy + 1) * 3 + (ox + 1));
            unsigned long long key = zhi | (unsigned long long)pid;
            if (key < kb[pix])                  // cheap L2-resident pre-check
                atomicMin(&kb[pix], key);
        }
    }
}

__global__ void resolve(const unsigned long long* __restrict__ kb,
                        const float* __restrict__ vox,
                        float* __restrict__ out) {
    int p = blockIdx.x * blockDim.x + threadIdx.x;
    if (p >= NPIX) return;
    unsigned long long key = kb[p];
    float r = 0.0f, g = 0.0f, b = 0.0f;
    if (key != EMPTY_KEY) {
        unsigned pid = (unsigned)(key & 0xFFFFFFFFull);
        unsigned n = pid / 9u;
        r = vox[n * 6 + 3];
        g = vox[n * 6 + 4];
        b = vox[n * 6 + 5];
    }
    out[p * 3 + 0] = r;
    out[p * 3 + 1] = g;
    out[p * 3 + 2] = b;
}

extern "C" void kernel_launch(void* const* d_in, const int* in_sizes, int n_in,
                              void* d_out, int out_size, void* d_ws, size_t ws_size,
                              hipStream_t stream) {
    const float* vox = (const float*)d_in[0];
    const float* m1  = (const float*)d_in[1];
    const float* m2  = (const float*)d_in[2];
    float* out = (float*)d_out;
    int N = in_sizes[0] / 6;

    unsigned long long* kb = (unsigned long long*)d_ws;   // 2 MB

    init_bufs<<<(NPIX + 255) / 256, 256, 0, stream>>>(kb);
    splat<<<(N + 255) / 256, 256, 0, stream>>>(vox, m1, m2, kb, N);
    resolve<<<(NPIX + 255) / 256, 256, 0, stream>>>(kb, vox, out);
}